// Round 4
// baseline (267.831 us; speedup 1.0000x reference)
//
#include <hip/hip_runtime.h>
#include <hip/hip_bf16.h>
#include <cstdint>
#include <cstddef>

// Problem constants (fixed by the reference)
#define BATCH 128
#define SEQ   512
#define DIM   1024
#define MROWS (BATCH * SEQ)          // 65536
#define NT    32                     // K sub-tiles of 32 (DIM/32)

typedef short short8 __attribute__((ext_vector_type(8)));
typedef __bf16 bf16x8 __attribute__((ext_vector_type(8)));
typedef float f32x4 __attribute__((ext_vector_type(4)));

// ---------- MFMA wrapper: accept either builtin signature (short8 or bf16x8) ----------
template <typename VA> struct other_frag { using type = bf16x8; };
template <> struct other_frag<bf16x8> { using type = short8; };

template <typename VA>
__device__ __forceinline__ auto try_mfma(VA a, VA b, f32x4 c, int)
    -> decltype(__builtin_amdgcn_mfma_f32_16x16x32_bf16(a, b, c, 0, 0, 0)) {
  return __builtin_amdgcn_mfma_f32_16x16x32_bf16(a, b, c, 0, 0, 0);
}
template <typename VA>
__device__ __forceinline__ f32x4 try_mfma(VA a, VA b, f32x4 c, long) {
  using O = typename other_frag<VA>::type;
  O a2 = __builtin_bit_cast(O, a);
  O b2 = __builtin_bit_cast(O, b);
  return __builtin_amdgcn_mfma_f32_16x16x32_bf16(a2, b2, c, 0, 0, 0);
}
__device__ __forceinline__ f32x4 mfma_bf16(short8 a, short8 b, f32x4 c) {
  return try_mfma(a, b, c, 0);
}

// ---------- helpers ----------
__device__ __forceinline__ unsigned short f32_to_bf16(float f) {
  union { float f; uint32_t u; } v; v.f = f;
  uint32_t u = v.u;
  u += 0x7FFFu + ((u >> 16) & 1u);   // round-to-nearest-even
  return (unsigned short)(u >> 16);
}

__device__ __forceinline__ float bf16_to_f32(unsigned short u) {
  union { uint32_t u; float f; } v; v.u = ((uint32_t)u) << 16; return v.f;
}

__device__ __forceinline__ void gload_lds16(const void* g, void* l) {
  __builtin_amdgcn_global_load_lds(
      (__attribute__((address_space(1))) void*)g,
      (__attribute__((address_space(3))) void*)l,
      16, 0, 0);
}

__device__ __forceinline__ float fast_tanh(float x) {
  x = fminf(fmaxf(x, -15.0f), 15.0f);
  float e = __expf(2.0f * x);
  return (e - 1.0f) / (e + 1.0f);
}

// ---------- kernel 1: cast X fp32 -> bf16 ----------
__global__ __launch_bounds__(256) void cast_x_kernel(const float* __restrict__ X,
                                                     unsigned short* __restrict__ Xb) {
  const int total8 = MROWS * DIM / 8;        // 8388608 groups of 8
  int idx = blockIdx.x * 256 + threadIdx.x;
  const int stride = 2048 * 256;
  for (int i = idx; i < total8; i += stride) {
    const f32x4* p = (const f32x4*)X + (size_t)i * 2;
    f32x4 a = p[0];
    f32x4 b = p[1];
    short8 o;
    o[0] = (short)f32_to_bf16(a[0]); o[1] = (short)f32_to_bf16(a[1]);
    o[2] = (short)f32_to_bf16(a[2]); o[3] = (short)f32_to_bf16(a[3]);
    o[4] = (short)f32_to_bf16(b[0]); o[5] = (short)f32_to_bf16(b[1]);
    o[6] = (short)f32_to_bf16(b[2]); o[7] = (short)f32_to_bf16(b[3]);
    *((short8*)Xb + i) = o;
  }
}

// ---------- kernel 2: W1 (D x D) -> W1t bf16 (transposed, [e][d]) ----------
__global__ __launch_bounds__(256) void w1t_kernel(const float* __restrict__ W1,
                                                  unsigned short* __restrict__ W1t) {
  __shared__ float tile[64][65];
  int bx = blockIdx.x & 15;    // e-tile
  int by = blockIdx.x >> 4;    // d-tile
  int t = threadIdx.x;
  int c = t & 63, r0 = t >> 6;
#pragma unroll
  for (int i = 0; i < 16; i++) {
    int r = i * 4 + r0;
    tile[r][c] = W1[(size_t)(by * 64 + r) * DIM + bx * 64 + c];
  }
  __syncthreads();
#pragma unroll
  for (int i = 0; i < 16; i++) {
    int r = i * 4 + r0;
    W1t[(size_t)(bx * 64 + r) * DIM + by * 64 + c] = f32_to_bf16(tile[c][r]);
  }
}

// ---------- kernel 3: u_last = X[:, -1, :] ----------
__global__ __launch_bounds__(256) void ulast_kernel(const float* __restrict__ X,
                                                    float* __restrict__ u_last) {
  int i = blockIdx.x * 256 + threadIdx.x;          // 32768 float4s
  int b = i >> 8;
  int d4 = i & 255;
  ((f32x4*)u_last)[i] = ((const f32x4*)X)[((size_t)b * SEQ + (SEQ - 1)) * 256 + d4];
}

// ---------- kernel 4: 256x256-tile pipelined GEMM + tanh + w2-dot -> scores ----------
// C[m][e] = sum_d Xb[m][d] * W1t[e][d];  scores[m] += sum_e tanh(C+b1[e]) * w2[e]
//
// 8 waves (2M x 4N), per-wave output 128x64. K pipelined in sub-tiles of 32
// with a depth-4 LDS ring (4 x (16KB A + 16KB B) = 128 KB). Counted vmcnt(8)
// once per sub-tile at the buffer switch (tail peeled 4 -> 0).
//
// m201-style phase-split: per sub-tile, 2 phases of
//   {stage-issue (2 gloads) + frag ds_reads -> s_barrier -> setprio(1) 16 MFMA
//    setprio(0) -> s_barrier}
// Phase A: stage A(S+3), read A frags mi0-3 + all B frags; MFMA mi0-3.
// Phase B: stage B(S+3), read A frags mi4-7;              MFMA mi4-7.
// Stage target = ring slot (S+3)&3 == (S-1)&3, proven drained by the top
// barrier (all waves' phase-B reads of S-1 completed before it).
//
// LDS layout per 16KB buffer ([256 rows][32 k] bf16): row pairs packed into
// 128-B stored rows; 16-B chunk index within stored row = logical ^ (srow&7).
// -> every 16-lane ds_read_b128 frag group hits each bank-quad exactly 2x
// (2-way = free).  Staging writes LDS linearly (global_load_lds) and applies
// the inverse (same) permutation to the *global* source address.
// Measured R2: SQ_LDS_BANK_CONFLICT == 0.
__global__ __launch_bounds__(512, 2) void gemm_score_kernel(
    const unsigned short* __restrict__ Xb,    // [MROWS][DIM]
    const unsigned short* __restrict__ W1t,   // [DIM][DIM]  (e-major)
    const float* __restrict__ b1,
    const float* __restrict__ w2,
    float* __restrict__ scores) {             // [MROWS]
  __shared__ __align__(16) char lds[131072];  // A: [0,64K), B: [64K,128K)

  const int tid = threadIdx.x;
  const int lane = tid & 63;
  const int w = tid >> 6;                     // wave 0..7
  const int wr = w >> 2, wc = w & 3;          // 2 x 4 wave grid

  // chunked XCD swizzle: 1024 blocks, 8 XCDs, n-fastest within each chunk
  const int bx = blockIdx.x;
  const int swz = (bx & 7) * 128 + (bx >> 3);
  const int m0 = (swz >> 2) * 256;
  const int n0 = (swz & 3) * 256;

  // ---- staging addresses.  chunk sc = (i*8+w)*64 + lane, LDS byte = sc*16.
  // inverse map: srow = sc>>3, ic = sc&7, j = ic ^ (srow&7),
  //              row = srow*2 + (j>>2), k16 = j&3.
  const unsigned short *a0Src, *a1Src, *b0Src, *b1Src;
  {
    int sc0 = w * 64 + lane;
    int sr0 = sc0 >> 3, j0 = (sc0 & 7) ^ (sr0 & 7);
    int row0 = sr0 * 2 + (j0 >> 2), c40 = j0 & 3;
    a0Src = Xb  + (size_t)(m0 + row0) * DIM + c40 * 8;
    b0Src = W1t + (size_t)(n0 + row0) * DIM + c40 * 8;
    int sc1 = (8 + w) * 64 + lane;
    int sr1 = sc1 >> 3, j1 = (sc1 & 7) ^ (sr1 & 7);
    int row1 = sr1 * 2 + (j1 >> 2), c41 = j1 & 3;
    a1Src = Xb  + (size_t)(m0 + row1) * DIM + c41 * 8;
    b1Src = W1t + (size_t)(n0 + row1) * DIM + c41 * 8;
  }
  const int dst0 = w * 1024;          // wave-uniform LDS dest base (bytes)
  const int dst1 = (8 + w) * 1024;

  // ---- fragment LDS byte offsets (within a buffer)
  int aOff[8];
#pragma unroll
  for (int mi = 0; mi < 8; mi++) {
    int row = wr * 128 + mi * 16 + (lane & 15);
    int srow = row >> 1;
    int ic = ((row & 1) * 4 + (lane >> 4)) ^ (srow & 7);
    aOff[mi] = srow * 128 + ic * 16;
  }
  int bOff[4];
#pragma unroll
  for (int ni = 0; ni < 4; ni++) {
    int row = wc * 64 + ni * 16 + (lane & 15);
    int srow = row >> 1;
    int ic = ((row & 1) * 4 + (lane >> 4)) ^ (srow & 7);
    bOff[ni] = 65536 + srow * 128 + ic * 16;   // B region
  }

  f32x4 acc[8][4];
#pragma unroll
  for (int mi = 0; mi < 8; mi++)
#pragma unroll
    for (int ni = 0; ni < 4; ni++)
      acc[mi][ni] = (f32x4){0.f, 0.f, 0.f, 0.f};

  short8 af[4], bfv[4];

#define STAGE_A(S) do {                                                 \
    const int bufS_ = ((S) & 3) * 16384;                                \
    const int ktS_ = (S) * 32;                                          \
    gload_lds16(a0Src + ktS_, lds + bufS_ + dst0);                      \
    gload_lds16(a1Src + ktS_, lds + bufS_ + dst1);                      \
  } while (0)

#define STAGE_B(S) do {                                                 \
    const int bufS_ = ((S) & 3) * 16384;                                \
    const int ktS_ = (S) * 32;                                          \
    gload_lds16(b0Src + ktS_, lds + 65536 + bufS_ + dst0);              \
    gload_lds16(b1Src + ktS_, lds + 65536 + bufS_ + dst1);              \
  } while (0)

#define KITER(S, VMSTR) do {                                            \
    asm volatile("s_waitcnt vmcnt(" VMSTR ")" ::: "memory");            \
    __builtin_amdgcn_s_barrier();                                       \
    __builtin_amdgcn_sched_barrier(0);                                  \
    const int buf_ = ((S) & 3) * 16384;                                 \
    /* ---- phase A ---- */                                             \
    if ((S) + 3 < NT) STAGE_A((S) + 3);                                 \
    _Pragma("unroll")                                                   \
    for (int mi = 0; mi < 4; mi++)                                      \
      af[mi] = *(const short8*)(lds + buf_ + aOff[mi]);                 \
    _Pragma("unroll")                                                   \
    for (int ni = 0; ni < 4; ni++)                                      \
      bfv[ni] = *(const short8*)(lds + buf_ + bOff[ni]);                \
    __builtin_amdgcn_s_barrier();                                       \
    __builtin_amdgcn_s_setprio(1);                                      \
    _Pragma("unroll")                                                   \
    for (int mi = 0; mi < 4; mi++)                                      \
      _Pragma("unroll")                                                 \
      for (int ni = 0; ni < 4; ni++)                                    \
        acc[mi][ni] = mfma_bf16(af[mi], bfv[ni], acc[mi][ni]);          \
    __builtin_amdgcn_s_setprio(0);                                      \
    __builtin_amdgcn_s_barrier();                                       \
    __builtin_amdgcn_sched_barrier(0);                                  \
    /* ---- phase B ---- */                                             \
    if ((S) + 3 < NT) STAGE_B((S) + 3);                                 \
    _Pragma("unroll")                                                   \
    for (int mi = 0; mi < 4; mi++)                                      \
      af[mi] = *(const short8*)(lds + buf_ + aOff[mi + 4]);             \
    __builtin_amdgcn_s_barrier();                                       \
    __builtin_amdgcn_s_setprio(1);                                      \
    _Pragma("unroll")                                                   \
    for (int mi = 0; mi < 4; mi++)                                      \
      _Pragma("unroll")                                                 \
      for (int ni = 0; ni < 4; ni++)                                    \
        acc[mi + 4][ni] = mfma_bf16(af[mi], bfv[ni], acc[mi + 4][ni]);  \
    __builtin_amdgcn_s_setprio(0);                                      \
  } while (0)

  // prologue: 3 sub-tiles in flight (12 wave-loads), A/B interleaved per tile
  STAGE_A(0); STAGE_B(0);
  STAGE_A(1); STAGE_B(1);
  STAGE_A(2); STAGE_B(2);

  for (int s = 0; s < NT - 2; ++s) KITER(s, "8");
  KITER(NT - 2, "4");
  KITER(NT - 1, "0");

#undef STAGE_A
#undef STAGE_B
#undef KITER

  // epilogue: scores[row] += sum over this wave's 64 cols of tanh(c + b1) * w2
  const int cg = lane >> 4;   // row group: rows cg*4 + j
  const int cl = lane & 15;   // col within fragment
#pragma unroll
  for (int mi = 0; mi < 8; mi++) {
    float p0 = 0.f, p1 = 0.f, p2 = 0.f, p3 = 0.f;
#pragma unroll
    for (int ni = 0; ni < 4; ni++) {
      int col = n0 + wc * 64 + ni * 16 + cl;
      float w2v = w2[col];
      float b1v = b1[col];
      p0 += fast_tanh(acc[mi][ni][0] + b1v) * w2v;
      p1 += fast_tanh(acc[mi][ni][1] + b1v) * w2v;
      p2 += fast_tanh(acc[mi][ni][2] + b1v) * w2v;
      p3 += fast_tanh(acc[mi][ni][3] + b1v) * w2v;
    }
#pragma unroll
    for (int off = 1; off < 16; off <<= 1) {
      p0 += __shfl_xor(p0, off);
      p1 += __shfl_xor(p1, off);
      p2 += __shfl_xor(p2, off);
      p3 += __shfl_xor(p3, off);
    }
    if (cl == 0) {
      int row = m0 + wr * 128 + mi * 16 + cg * 4;
      atomicAdd(&scores[row + 0], p0);
      atomicAdd(&scores[row + 1], p1);
      atomicAdd(&scores[row + 2], p2);
      atomicAdd(&scores[row + 3], p3);
    }
  }
}

// ---------- kernel 5: masked softmax + u_att (reads bf16 Xb) ----------
__global__ __launch_bounds__(256) void attn_uatt_kernel(
    const unsigned short* __restrict__ Xb,
    const float* __restrict__ scores,
    const int* __restrict__ mask,
    float* __restrict__ u_att) {
  const int b = blockIdx.x;
  const int half = blockIdx.y;            // d-range [half*512, half*512+512)
  const int tid = threadIdx.x;
  const int lane = tid & 63;
  const int wave = tid >> 6;

  __shared__ float attn[SEQ];
  __shared__ float rbuf[4];
  __shared__ float part[3][64 * 9];       // padded stride 9

  float s0 = scores[(size_t)b * SEQ + tid];
  float s1 = scores[(size_t)b * SEQ + 256 + tid];
  if (mask[(size_t)b * SEQ + tid]) s0 = -1000000000.0f;
  if (mask[(size_t)b * SEQ + 256 + tid]) s1 = -1000000000.0f;

  float mx = fmaxf(s0, s1);
#pragma unroll
  for (int off = 1; off < 64; off <<= 1) mx = fmaxf(mx, __shfl_xor(mx, off));
  if (lane == 0) rbuf[wave] = mx;
  __syncthreads();
  mx = fmaxf(fmaxf(rbuf[0], rbuf[1]), fmaxf(rbuf[2], rbuf[3]));

  float p0 = expf(s0 - mx), p1 = expf(s1 - mx);
  float sm = p0 + p1;
#pragma unroll
  for (int off = 1; off < 64; off <<= 1) sm += __shfl_xor(sm, off);
  __syncthreads();
  if (lane == 0) rbuf[wave] = sm;
  __syncthreads();
  sm = rbuf[0] + rbuf[1] + rbuf[2] + rbuf[3];
  float inv = 1.0f / sm;
  attn[tid] = p0 * inv;
  attn[tid + 256] = p1 * inv;
  __syncthreads();

  // u_att[b][d] = sum_s attn[s] * X[b][s][d]; block covers 512 d (64 chunks of 8)
  const int col = tid & 63;            // 8-bf16 chunk within the half
  const int sh = tid >> 6;             // s-range split: [sh*128, sh*128+128)
  const short8* Xp = (const short8*)Xb + (size_t)b * SEQ * (DIM / 8) + half * 64 + col;
  float a[8] = {0.f, 0.f, 0.f, 0.f, 0.f, 0.f, 0.f, 0.f};
  for (int s = sh * 128; s < sh * 128 + 128; s++) {
    short8 v = Xp[(size_t)s * (DIM / 8)];
    float wgt = attn[s];
#pragma unroll
    for (int j = 0; j < 8; j++)
      a[j] += wgt * bf16_to_f32((unsigned short)v[j]);
  }
  if (sh) {
#pragma unroll
    for (int j = 0; j < 8; j++) part[sh - 1][col * 9 + j] = a[j];
  }
  __syncthreads();
  if (sh == 0) {
#pragma unroll
    for (int j = 0; j < 8; j++)
      a[j] += part[0][col * 9 + j] + part[1][col * 9 + j] + part[2][col * 9 + j];
    f32x4 lo = {a[0], a[1], a[2], a[3]};
    f32x4 hi = {a[4], a[5], a[6], a[7]};
    f32x4* dst = (f32x4*)(u_att + (size_t)b * DIM + half * 512 + col * 8);
    dst[0] = lo;
    dst[1] = hi;
  }
}

// ---------- launcher ----------
extern "C" void kernel_launch(void* const* d_in, const int* in_sizes, int n_in,
                              void* d_out, int out_size, void* d_ws, size_t ws_size,
                              hipStream_t stream) {
  const float* X    = (const float*)d_in[0];   // [128][512][1024] fp32
  const int*   mask = (const int*)d_in[1];     // [128][512] int32 (bool)
  const float* W1   = (const float*)d_in[2];   // [1024][1024]
  const float* b1   = (const float*)d_in[3];   // [1024]
  const float* w2   = (const float*)d_in[4];   // [1024]

  float* out    = (float*)d_out;
  float* u_last = out;                          // [128][1024]
  float* u_att  = out + BATCH * DIM;            // [128][1024]

  char* ws = (char*)d_ws;
  unsigned short* Xb  = (unsigned short*)ws;                                // 128 MB
  unsigned short* W1t = (unsigned short*)(ws + (size_t)MROWS * DIM * 2);    // 2 MB
  float* scores = (float*)(ws + (size_t)MROWS * DIM * 2 + (size_t)DIM * DIM * 2); // 256 KB

  hipMemsetAsync(scores, 0, MROWS * sizeof(float), stream);
  hipLaunchKernelGGL(cast_x_kernel, dim3(2048), dim3(256), 0, stream, X, Xb);
  hipLaunchKernelGGL(w1t_kernel, dim3(256), dim3(256), 0, stream, W1, W1t);
  hipLaunchKernelGGL(ulast_kernel, dim3(128), dim3(256), 0, stream, X, u_last);
  hipLaunchKernelGGL(gemm_score_kernel, dim3(1024), dim3(512), 0, stream,
                     Xb, W1t, b1, w2, scores);
  hipLaunchKernelGGL(attn_uatt_kernel, dim3(128, 2), dim3(256), 0, stream,
                     Xb, scores, mask, u_att);
}